// Round 4
// baseline (1703.062 us; speedup 1.0000x reference)
//
#include <hip/hip_runtime.h>
#include <cstdint>
#include <cstddef>

// ===========================================================================
// ActionDecoder on MI355X — round 16: ACK-FREE release.
// r15 (1204us lstm) chain model: ack(1RT) + flag one-way(0.5RT) + poll
// detect(1RT) + A-load(1RT) + compute ~ 5400cy/step. This round removes the
// producer-side store-ack RT from the consumer-visible chain:
//   - ADVISORY per-WG flag (fire-and-forget, NO bar2, NO vmcnt drain): pure
//     latency hint, gates the consumer's expensive data read (thin 4B spin,
//     the r12 lesson).
//   - TRUTH-IN-DATA: h published as r13's proven tagged 8B pairs
//     {f16x2 | tag}, tag = 0x5A5A0000 + t + 1 (collision-free vs 0xAA
//     poison and any GEMM float bit pattern). Consumer verifies 16 tags
//     after the A-load; re-loads only on a lost race (rare: flag+data are
//     issued together, detect adds ~1RT of slack).
//   - producer's own store-ack now retires inside its own poll window.
//   - Spart double-buffered by t&1 (80KB) replaces bar2's intra-WG ordering.
//   - hbuf parity-1 plane OVERLAYS GX0 (BG-aligned: hbuf1 bytes for batch b
//     sit inside GX0 rows of b's own BG). Safe: WG flag=1 is published after
//     a __syncthreads that drains its gxv hoist; any h_1 store requires
//     poll(0) = all 16 flags of the SAME BG (4 waves x 4 flags + bar1).
//     ws footprint unchanged vs r15.
// Kept from r15: topology (64 WGs, BG=wg>>4 x CG=wg&15, wave=K-chunk),
// B-frags 128 VGPRs, rotated Spart write/read (conflicts 2.5e7 -> 8.4e6),
// 4-flag poll, P-prefetch after release (poll-shadow), sc1 relaxed
// agent-scope accessors.
// ===========================================================================

typedef _Float16     f16x8 __attribute__((ext_vector_type(8)));
typedef _Float16     f16x2 __attribute__((ext_vector_type(2)));
typedef float        f32x4 __attribute__((ext_vector_type(4)));
typedef float        f32x2 __attribute__((ext_vector_type(2)));
typedef unsigned int u32x4 __attribute__((ext_vector_type(4)));

#define TPB 256
#define NWG 64
#define TAGBASE 0x5A5A0000u

// ---- ws layout (bytes) ----
#define WS_GX0   0          // 64*2048 f32   = 524288  (also hosts hbuf1 plane)
#define WS_P     524288     // 512*2048 f32  = 4194304
#define WS_HN    4718592    // 64*512 f32    = 131072
#define WS_HBUF0 4849664    // 64*256 u64    = 131072  (tagged pairs, parity 0)
#define WS_FLAGS 4980736    // 64 WG x 256B  = 16384

__device__ __forceinline__ float sigm_(float x) { return 1.f / (1.f + __expf(-x)); }
__device__ __forceinline__ float tanh_(float x) {
    const float e = __expf(-2.f * fabsf(x));
    return copysignf((1.f - e) / (1.f + e), x);
}

// agent-scope (IC-coherent) relaxed accessors
__device__ __forceinline__ void st_ic_u32(unsigned int* p, unsigned int v) {
    __hip_atomic_store(p, v, __ATOMIC_RELAXED, __HIP_MEMORY_SCOPE_AGENT);
}
__device__ __forceinline__ unsigned int ld_ic_u32(const unsigned int* p) {
    return __hip_atomic_load(p, __ATOMIC_RELAXED, __HIP_MEMORY_SCOPE_AGENT);
}
__device__ __forceinline__ void st_ic_u64(unsigned long long* p, unsigned long long v) {
    __hip_atomic_store(p, v, __ATOMIC_RELAXED, __HIP_MEMORY_SCOPE_AGENT);
}

// ---------------------------------------------------------------------------
// Generic f32 tiled GEMM: C[M,N] = A[M,K] @ B[N,K]^T (+bias1+bias2 on z==0).
// ---------------------------------------------------------------------------
__global__ void gemm_nt_bias(const float* __restrict__ A, int lda,
                             const float* __restrict__ B, int ldb,
                             float* __restrict__ C, int ldc, int K,
                             const float* __restrict__ bias1,
                             const float* __restrict__ bias2)
{
    __shared__ float As[32 * 68];
    __shared__ float Bs[32 * 68];
    const int tid = threadIdx.x;
    const int m0 = blockIdx.y * 64, n0 = blockIdx.x * 64;
    const int kchunk = K / gridDim.z;
    const int kbeg = blockIdx.z * kchunk, kend = kbeg + kchunk;
    const int tr = tid >> 4, tc = tid & 15;
    float acc[4][4] = {};

    for (int k0 = kbeg; k0 < kend; k0 += 32) {
        __syncthreads();
        #pragma unroll
        for (int idx = tid; idx < 2048; idx += TPB) {
            const int r = idx >> 5, kk = idx & 31;
            As[kk * 68 + r] = A[(size_t)(m0 + r) * lda + k0 + kk];
            Bs[kk * 68 + r] = B[(size_t)(n0 + r) * ldb + k0 + kk];
        }
        __syncthreads();
        #pragma unroll
        for (int kk = 0; kk < 32; ++kk) {
            const f32x4 a = *(const f32x4*)&As[kk * 68 + tr * 4];
            const f32x4 b = *(const f32x4*)&Bs[kk * 68 + tc * 4];
            #pragma unroll
            for (int i = 0; i < 4; ++i)
                #pragma unroll
                for (int j = 0; j < 4; ++j)
                    acc[i][j] = fmaf(a[i], b[j], acc[i][j]);
        }
    }

    const bool split = (gridDim.z > 1);
    #pragma unroll
    for (int i = 0; i < 4; ++i) {
        const int m = m0 + tr * 4 + i;
        #pragma unroll
        for (int j = 0; j < 4; ++j) {
            const int n = n0 + tc * 4 + j;
            float v = acc[i][j];
            if (blockIdx.z == 0) {
                if (bias1) v += bias1[n];
                if (bias2) v += bias2[n];
            }
            if (split) atomicAdd(&C[(size_t)m * ldc + n], v);
            else       C[(size_t)m * ldc + n] = v;
        }
    }
}

// ---------------------------------------------------------------------------
// LSTM recurrence. 64 WGs x 256 threads. 2-D partition, split-K per wave.
// hbuf planes: parity 0 at hbuf0 ([64][256] u64); parity 1 overlays GX0 with
// BG-aligned mapping: addr1(b,cp) = hbuf1 + (b>>4)*16384 + (b&15)*256 + cp.
// Tag: h_t carries TAGBASE + t + 1. Flags are ADVISORY only.
// ---------------------------------------------------------------------------
__global__ void __launch_bounds__(TPB, 1)
lstm_seq(const float* __restrict__ Whh,   // [2048,512] f32
         const float* GX0,                // [64,2048] f32 (ws; aliases hbuf1)
         const float* __restrict__ P,     // [512,2048] f32 (ws)
         const int*   __restrict__ x2,    // [64,512]
         const int*   __restrict__ lens,  // [64]
         unsigned long long* hbuf0,       // parity-0 tagged pairs (ws)
         unsigned long long* hbuf1,       // parity-1 tagged pairs (= GX0 mem)
         float*       __restrict__ hn,    // [64,512] f32 (ws)
         unsigned int* flags)             // [64 wg] spaced 256B, advisory
{
    // Spart[par][wv][rowloc(128)][16 batch slots + pad4] — double buffered
    __shared__ float Spart[2 * 4 * 128 * 20];   // 81920 B

    const int tid = threadIdx.x, wg = blockIdx.x;
    const int lane = tid & 63, wv = tid >> 6;
    const int BG = wg >> 4;               // batch group 0..3
    const int CG = wg & 15;               // col group 0..15
    const int m16 = lane & 15, q = lane >> 4;

    // ---- gate-thread geometry: thread -> (batch-loc, 2 adjacent cols) ----
    const int bl  = tid >> 4;             // 0..15 batch-local
    const int cq  = (tid & 15) * 2;       // 0,2,..,30 col-local
    const int b   = BG * 16 + bl;
    const int col = CG * 32 + cq;
    const int cp  = CG * 16 + (tid & 15); // col-pair 0..255
    const int last = lens[b] - 1;
    const int* toks = x2 + b * 512;

    // ---- time-invariant gate inputs from GX0 (hoisted BEFORE flag=1) ----
    f32x2 gxv[4];
    {
        const float* gx = GX0 + (size_t)b * 2048 + col;
        #pragma unroll
        for (int g = 0; g < 4; ++g) gxv[g] = *(const f32x2*)(gx + g * 512);
    }

    // ---- producer destinations / consumer bases for both parities ----
    unsigned long long* hd0 = hbuf0 + (size_t)b * 256 + cp;
    unsigned long long* hd1 = hbuf1 + (size_t)BG * 16384 + (size_t)bl * 256 + cp;
    const unsigned long long* ab0 =
        hbuf0 + (size_t)(BG * 16 + m16) * 256 + wv * 64 + q * 4;
    const unsigned long long* ab1 =
        hbuf1 + (size_t)BG * 16384 + (size_t)m16 * 256 + wv * 64 + q * 4;

    // ---- publish h_0 = 0 with tag TAGBASE+1 (parity 0, fire-and-forget) ----
    st_ic_u64(hd0, (unsigned long long)(TAGBASE + 1u) << 32);

    // drain gxv hoist (+ h_0) before advisory flag=1: this ordering is what
    // makes the hbuf1-over-GX0 overlay safe (see header).
    __syncthreads();
    unsigned int* myflag = flags + (size_t)wg * 64;   // 256B spacing
    if (tid == 0) st_ic_u32(myflag, 1u);

    // wave wv consumes h-cols [128wv,128wv+128) of batch group BG,
    // produced by WGs (BG, 4wv+0..3): poll those 4 advisory flags (lane&3).
    const unsigned int* pollp =
        flags + (size_t)(BG * 16 + wv * 4 + (lane & 3)) * 64;

    // ---- B fragments: wave wv's 8 n-tiles x 4 K-frags (128 VGPRs) ----
    f16x8 bfr[8][4];
    #pragma unroll
    for (int n = 0; n < 8; ++n) {
        const int rr = n * 16 + m16;
        const int gr = (rr >> 5) * 512 + CG * 32 + (rr & 31);
        const float* wrow = Whh + (size_t)gr * 512 + wv * 128 + q * 8;
        #pragma unroll
        for (int ks = 0; ks < 4; ++ks) {
            const f32x4 w0 = *(const f32x4*)(wrow + ks * 32);
            const f32x4 w1 = *(const f32x4*)(wrow + ks * 32 + 4);
            f16x8 bv;
            #pragma unroll
            for (int e = 0; e < 4; ++e) {
                bv[e]     = (_Float16)w0[e];
                bv[4 + e] = (_Float16)w1[e];
            }
            bfr[n][ks] = bv;
        }
    }

    // ---- P-row pipeline: ppv = row for step t; refilled post-release ----
    int tok1;
    f32x2 ppv[4];
    {
        const int tok0 = toks[0];
        const float* pp = P + (size_t)tok0 * 2048 + col;
        #pragma unroll
        for (int g = 0; g < 4; ++g) ppv[g] = *(const f32x2*)(pp + g * 512);
        tok1 = toks[1];
    }

    float c0 = 0.f, c1 = 0.f;

    for (int t = 0; t < 512; ++t) {
        const unsigned int tgt  = (unsigned int)(t + 1);
        const unsigned int tagv = TAGBASE + (unsigned int)(t + 1);

        // ---- advisory poll: thin 4B spin on 4 producer flags ----
        while (true) {
            const unsigned int v = ld_ic_u32(pollp);
            if (__all((int)(v >= tgt))) break;
        }
        asm volatile("" ::: "memory");

        const unsigned long long* hs = (t & 1) ? ab1 : ab0;

        // ---- tagged A-load (truth): 8 x dwordx4 sc1; verify 16 embedded
        //      tags == tagv exactly; re-load on a lost race (rare) ----
        u32x4 r0, r1, r2, r3, r4, r5, r6, r7;
        while (true) {
            asm volatile(
                "global_load_dwordx4 %0, %8, off sc1\n\t"
                "global_load_dwordx4 %1, %8, off offset:16 sc1\n\t"
                "global_load_dwordx4 %2, %8, off offset:128 sc1\n\t"
                "global_load_dwordx4 %3, %8, off offset:144 sc1\n\t"
                "global_load_dwordx4 %4, %8, off offset:256 sc1\n\t"
                "global_load_dwordx4 %5, %8, off offset:272 sc1\n\t"
                "global_load_dwordx4 %6, %8, off offset:384 sc1\n\t"
                "global_load_dwordx4 %7, %8, off offset:400 sc1\n\t"
                "s_waitcnt vmcnt(0)"
                : "=&v"(r0), "=&v"(r1), "=&v"(r2), "=&v"(r3),
                  "=&v"(r4), "=&v"(r5), "=&v"(r6), "=&v"(r7)
                : "v"(hs)
                : "memory");
            const unsigned int d =
                (r0[1] ^ tagv) | (r0[3] ^ tagv) | (r1[1] ^ tagv) | (r1[3] ^ tagv) |
                (r2[1] ^ tagv) | (r2[3] ^ tagv) | (r3[1] ^ tagv) | (r3[3] ^ tagv) |
                (r4[1] ^ tagv) | (r4[3] ^ tagv) | (r5[1] ^ tagv) | (r5[3] ^ tagv) |
                (r6[1] ^ tagv) | (r6[3] ^ tagv) | (r7[1] ^ tagv) | (r7[3] ^ tagv);
            if (__all((int)(d == 0u))) break;
        }

        // ---- strip tags -> A fragments (values in even dwords) ----
        u32x4 fw0 = {r0[0], r0[2], r1[0], r1[2]};
        u32x4 fw1 = {r2[0], r2[2], r3[0], r3[2]};
        u32x4 fw2 = {r4[0], r4[2], r5[0], r5[2]};
        u32x4 fw3 = {r6[0], r6[2], r7[0], r7[2]};
        f16x8 af[4] = {
            __builtin_bit_cast(f16x8, fw0), __builtin_bit_cast(f16x8, fw1),
            __builtin_bit_cast(f16x8, fw2), __builtin_bit_cast(f16x8, fw3)
        };

        // ---- 32 MFMA: 8 n-tiles x 4 K-steps (my K-chunk partial) ----
        f32x4 acc[8] = {};
        #pragma unroll
        for (int ks = 0; ks < 4; ++ks)
            #pragma unroll
            for (int n = 0; n < 8; ++n)
                acc[n] = __builtin_amdgcn_mfma_f32_16x16x32_f16(
                    af[ks], bfr[n][ks], acc[n], 0, 0, 0);

        // ---- write partial S to LDS (parity buf), granule rotated ----
        float* sp = Spart + (t & 1) * 10240;
        {
            const int cl = lane & 15, gq = lane >> 4;
            #pragma unroll
            for (int n = 0; n < 8; ++n) {
                const int row = wv * 128 + n * 16 + cl;
                *(f32x4*)&sp[row * 20 + ((gq + (row >> 3)) & 3) * 4] = acc[n];
            }
        }
        __syncthreads();                  // split-K reduction barrier (only one)

        // ---- gate inputs: sum 4 wave-partials per gate value (2-way) ----
        f32x2 sv[4];
        #pragma unroll
        for (int g = 0; g < 4; ++g) {
            f32x2 s = {0.f, 0.f};
            #pragma unroll
            for (int w = 0; w < 4; ++w) {
                const int r0r = w * 128 + g * 32 + cq;
                const int base =
                    r0r * 20 + (((bl >> 2) + (r0r >> 3)) & 3) * 4 + (bl & 3);
                s[0] += sp[base];
                s[1] += sp[base + 20]; // col cq+1: same rotation (cq even)
            }
            sv[g] = s;
        }

        // ---- gates (2 adjacent cols of one batch per thread) ----
        float hv[2];
        #pragma unroll
        for (int p = 0; p < 2; ++p) {
            const float iv = sigm_(sv[0][p] + gxv[0][p] + ppv[0][p]);
            const float fv = sigm_(sv[1][p] + gxv[1][p] + ppv[1][p]);
            const float gv = tanh_(sv[2][p] + gxv[2][p] + ppv[2][p]);
            const float ov = sigm_(sv[3][p] + gxv[3][p] + ppv[3][p]);
            float& c = p ? c1 : c0;
            c = fv * c + iv * gv;
            hv[p] = ov * tanh_(c);
        }

        // ---- fire-and-forget tagged publish (tag = tagv+1 for h_{t+1}) ----
        f16x2 hh; hh[0] = (_Float16)hv[0]; hh[1] = (_Float16)hv[1];
        const unsigned long long pv =
            ((unsigned long long)(tagv + 1u) << 32) |
            (unsigned long long)__builtin_bit_cast(unsigned int, hh);
        st_ic_u64(((t + 1) & 1) ? hd1 : hd0, pv);

        if (t == last) {
            f32x2 o; o[0] = hv[0]; o[1] = hv[1];
            *(f32x2*)(hn + (size_t)b * 512 + col) = o;
        }

        // ---- advisory flag: fire-and-forget, NO drain, NO bar2 ----
        if (tid == 0) st_ic_u32(myflag, (unsigned int)(t + 2));

        // ---- NEXT step's P row prefetch: latency parks in the poll
        //      window (drained by the A-load's vmcnt(0)) ----
        {
            const float* pn = P + (size_t)tok1 * 2048 + col;
            #pragma unroll
            for (int g = 0; g < 4; ++g)
                ppv[g] = *(const f32x2*)(pn + g * 512);
            tok1 = toks[t < 510 ? t + 2 : 511];
        }
    }
}

// ---------------------------------------------------------------------------
extern "C" void kernel_launch(void* const* d_in, const int* in_sizes, int n_in,
                              void* d_out, int out_size, void* d_ws, size_t ws_size,
                              hipStream_t stream)
{
    const float* x1    = (const float*)d_in[0];   // [64,1024]
    const int*   x2    = (const int*)  d_in[1];   // [64,512]
    const int*   lens  = (const int*)  d_in[2];   // [64]
    const float* emb   = (const float*)d_in[3];   // [512,128]
    const float* W_ih  = (const float*)d_in[4];   // [2048,1152]
    const float* W_hh  = (const float*)d_in[5];   // [2048,512]
    const float* b_ih  = (const float*)d_in[6];   // [2048]
    const float* b_hh  = (const float*)d_in[7];   // [2048]
    const float* W_act = (const float*)d_in[8];   // [512,512]
    const float* b_act = (const float*)d_in[9];   // [512]
    float* out = (float*)d_out;                   // [64,512]

    char* ws = (char*)d_ws;
    float*              GX0   = (float*)(ws + WS_GX0);
    float*              P     = (float*)(ws + WS_P);
    float*              hn    = (float*)(ws + WS_HN);
    unsigned long long* hbuf0 = (unsigned long long*)(ws + WS_HBUF0);
    unsigned long long* hbuf1 = (unsigned long long*)(ws + WS_GX0);
    unsigned int*       flags = (unsigned int*)(ws + WS_FLAGS);

    // zero flags + k-split accumulators (ws/out poisoned 0xAA each call).
    // hbuf0 poison is tag-safe (0xAAAAAAAA != TAGBASE+k); hbuf1 plane is
    // GX0 memory: zeroed here, then GEMM floats, then tagged stores.
    hipMemsetAsync(flags, 0, 16384, stream);
    hipMemsetAsync(GX0, 0, 64 * 2048 * sizeof(float), stream);
    hipMemsetAsync(out, 0, 64 * 512 * sizeof(float), stream);

    // GX0 = x1 @ W_ih[:, :1024]^T + b_ih + b_hh    (K=1024, 4-way K-split)
    gemm_nt_bias<<<dim3(32, 1, 4), TPB, 0, stream>>>(
        x1, 1024, W_ih, 1152, GX0, 2048, 1024, b_ih, b_hh);
    // P = emb @ W_ih[:, 1024:]^T                   (K=128)
    gemm_nt_bias<<<dim3(32, 8, 1), TPB, 0, stream>>>(
        emb, 128, W_ih + 1024, 1152, P, 2048, 128, nullptr, nullptr);

    // recurrence: 64 WGs, advisory flags + truth-in-data tagged publish
    lstm_seq<<<NWG, TPB, 0, stream>>>(W_hh, GX0, P, x2, lens,
                                      hbuf0, hbuf1, hn, flags);

    // out = hn @ W_act^T + b_act                   (K=512, 4-way K-split)
    gemm_nt_bias<<<dim3(8, 1, 4), TPB, 0, stream>>>(
        hn, 512, W_act, 512, out, 512, 512, b_act, nullptr);
}

// Round 7
// 1347.124 us; speedup vs baseline: 1.2642x; 1.2642x over previous
//
#include <hip/hip_runtime.h>
#include <cstdint>
#include <cstddef>

// ===========================================================================
// ActionDecoder on MI355X — round 19: r15 proven core (1204us lstm, all-sc1,
// 64 WGs, no registration) + three independent, semantics-preserving cuts.
// r17/r18 (XCD cliques, sc0) died twice with zero kernel signal — direction
// abandoned; every sync primitive here is r7..r15-proven.
//  (1) STAGGERED 2-SLOT FLAG POLL: r15's spin samples once per IC RT
//      (~1100cy) -> detection quantization ~U(0,RT). Two poll loads offset
//      by s_sleep 8 (~512cy ~ RT/2), alternating s_waitcnt vmcnt(1) on the
//      older slot, halve the sampling period (phase-stable: reissue cost
//      << RT/2). Exit may leave one load in flight: its registers are kept
//      live as dummy inputs to the A-load block, whose vmcnt(0) drains it.
//  (2) MERGED PROLOGUE: GX0-GEMM (128 blk) + P-GEMM (256 blk) in ONE
//      384-block launch (blockIdx decode) — one less launch boundary,
//      overlapped execution.
//  (3) FUSED EPILOGUE: out = hn @ W_act^T + b_act inside lstm_seq. hn
//      stores become sc1 u64 (covered by the existing bar2-drain -> flag
//      release order); after the t-loop each clique polls its 16 flags
//      >= 513, stages hn[16][512] into the now-free Spart (pitch 516,
//      conflict-free), each thread dots its 2 out-cols. Removes the 4th
//      launch + the out memset.
// Core unchanged from r15: 64 WGs (BG=wg>>4, CG=wg&15), wave wv = K-chunk
// [128wv,128wv+128), B-frags in 128 VGPRs, rotated Spart split-K (2-way
// banks, conflicts 2.5e7->8.4e6), two barriers/step, single WG flag at
// 256B spacing, 4KB sc1 A-load, P-prefetch post-release in the poll shadow.
// ===========================================================================

typedef _Float16     f16x8 __attribute__((ext_vector_type(8)));
typedef _Float16     f16x2 __attribute__((ext_vector_type(2)));
typedef float        f32x4 __attribute__((ext_vector_type(4)));
typedef float        f32x2 __attribute__((ext_vector_type(2)));
typedef unsigned int u32x4 __attribute__((ext_vector_type(4)));

#define TPB 256
#define NWG 64

// ---- ws layout (bytes) ----
#define WS_GX0   0          // 64*2048 f32   = 524288
#define WS_P     524288     // 512*2048 f32  = 4194304
#define WS_HN    4718592    // 64*512 f32    = 131072
#define WS_HBUF  4849664    // 2*64*512 f16  = 131072
#define WS_FLAGS 4980736    // 64 WG x 256B  = 16384

__device__ __forceinline__ float sigm_(float x) { return 1.f / (1.f + __expf(-x)); }
__device__ __forceinline__ float tanh_(float x) {
    const float e = __expf(-2.f * fabsf(x));
    return copysignf((1.f - e) / (1.f + e), x);
}

// agent-scope (IC-coherent) relaxed accessors — proven r3..r15 primitives
__device__ __forceinline__ void st_ic_u32(unsigned int* p, unsigned int v) {
    __hip_atomic_store(p, v, __ATOMIC_RELAXED, __HIP_MEMORY_SCOPE_AGENT);
}
__device__ __forceinline__ unsigned int ld_ic_u32(const unsigned int* p) {
    return __hip_atomic_load(p, __ATOMIC_RELAXED, __HIP_MEMORY_SCOPE_AGENT);
}
__device__ __forceinline__ void st_ic_u64(unsigned long long* p, unsigned long long v) {
    __hip_atomic_store(p, v, __ATOMIC_RELAXED, __HIP_MEMORY_SCOPE_AGENT);
}

// ---------------------------------------------------------------------------
// Merged prologue GEMM (one launch, 384 blocks):
//   blocks 0..127 : GX0 = x1[64,1024] @ W_ih[:, :1024]^T (+b_ih+b_hh on z==0)
//                   4-way K-split (z = bid>>5), atomicAdd into zeroed GX0
//   blocks 128..383: P = emb[512,128] @ W_ih[:, 1024:]^T, direct store
// ---------------------------------------------------------------------------
__global__ void __launch_bounds__(TPB, 1)
gemm_prologue(const float* __restrict__ x1,   // [64,1024]
              const float* __restrict__ emb,  // [512,128]
              const float* __restrict__ W_ih, // [2048,1152]
              const float* __restrict__ b_ih, // [2048]
              const float* __restrict__ b_hh, // [2048]
              float* __restrict__ GX0,        // [64,2048] (pre-zeroed)
              float* __restrict__ P)          // [512,2048]
{
    __shared__ float As[32 * 68];
    __shared__ float Bs[32 * 68];
    const int tid = threadIdx.x;
    const int bid = blockIdx.x;

    const float *A, *B, *bias1 = nullptr, *bias2 = nullptr;
    float* C;
    int lda, ldb, ldc, m0, n0, kbeg, kend;
    bool split;
    if (bid < 128) {
        const int z = bid >> 5;
        A = x1;  lda = 1024; B = W_ih; ldb = 1152;
        C = GX0; ldc = 2048;
        m0 = 0; n0 = (bid & 31) * 64;
        kbeg = z * 256; kend = kbeg + 256; split = true;
        if (z == 0) { bias1 = b_ih; bias2 = b_hh; }
    } else {
        const int t2 = bid - 128;
        A = emb; lda = 128; B = W_ih + 1024; ldb = 1152;
        C = P;   ldc = 2048;
        m0 = (t2 >> 5) * 64; n0 = (t2 & 31) * 64;
        kbeg = 0; kend = 128; split = false;
    }

    const int tr = tid >> 4, tc = tid & 15;
    float acc[4][4] = {};

    for (int k0 = kbeg; k0 < kend; k0 += 32) {
        __syncthreads();
        #pragma unroll
        for (int idx = tid; idx < 2048; idx += TPB) {
            const int r = idx >> 5, kk = idx & 31;
            As[kk * 68 + r] = A[(size_t)(m0 + r) * lda + k0 + kk];
            Bs[kk * 68 + r] = B[(size_t)(n0 + r) * ldb + k0 + kk];
        }
        __syncthreads();
        #pragma unroll
        for (int kk = 0; kk < 32; ++kk) {
            const f32x4 a = *(const f32x4*)&As[kk * 68 + tr * 4];
            const f32x4 b = *(const f32x4*)&Bs[kk * 68 + tc * 4];
            #pragma unroll
            for (int i = 0; i < 4; ++i)
                #pragma unroll
                for (int j = 0; j < 4; ++j)
                    acc[i][j] = fmaf(a[i], b[j], acc[i][j]);
        }
    }

    #pragma unroll
    for (int i = 0; i < 4; ++i) {
        const int m = m0 + tr * 4 + i;
        #pragma unroll
        for (int j = 0; j < 4; ++j) {
            const int n = n0 + tc * 4 + j;
            float v = acc[i][j];
            if (bias1) v += bias1[n];
            if (bias2) v += bias2[n];
            if (split) atomicAdd(&C[(size_t)m * ldc + n], v);
            else       C[(size_t)m * ldc + n] = v;
        }
    }
}

// ---------------------------------------------------------------------------
// LSTM recurrence + fused action head. 64 WGs x 256 threads.
// ---------------------------------------------------------------------------
__global__ void __launch_bounds__(TPB, 1)
lstm_seq(const float* __restrict__ Whh,   // [2048,512] f32
         const float* __restrict__ GX0,   // [64,2048] f32 (ws)
         const float* __restrict__ P,     // [512,2048] f32 (ws)
         const int*   __restrict__ x2,    // [64,512]
         const int*   __restrict__ lens,  // [64]
         _Float16*    hbuf,               // [2][64*512] f16 (ws, IC-resident)
         float*       hn,                 // [64,512] f32 (ws, sc1 medium)
         unsigned int* flags,             // [64 wg] spaced 256B
         const float* __restrict__ W_act, // [512,512]
         const float* __restrict__ b_act, // [512]
         float*       __restrict__ out)   // [64,512] (d_out)
{
    // Spart[wv][rowloc(128)][16 batch slots + pad4] f32 = 40960 B
    // (reused post-loop as hnL[16][516] = 33024 B for the fused epilogue)
    __shared__ float Spart[4 * 128 * 20];

    const int tid = threadIdx.x, wg = blockIdx.x;
    const int lane = tid & 63, wv = tid >> 6;
    const int BG = wg >> 4;               // batch group 0..3
    const int CG = wg & 15;               // col group 0..15
    const int m16 = lane & 15, q = lane >> 4;

    // ---- gate-thread geometry: thread -> (batch-loc, 2 adjacent cols) ----
    const int bl  = tid >> 4;             // 0..15 batch-local
    const int cq  = (tid & 15) * 2;       // 0,2,..,30 col-local
    const int b   = BG * 16 + bl;
    const int col = CG * 32 + cq;
    const int last = lens[b] - 1;
    const int* toks = x2 + b * 512;

    // ---- time-invariant gate inputs from GX0 (hoisted) ----
    f32x2 gxv[4];
    {
        const float* gx = GX0 + (size_t)b * 2048 + col;
        #pragma unroll
        for (int g = 0; g < 4; ++g) gxv[g] = *(const f32x2*)(gx + g * 512);
    }

    // ---- publish h_0 = 0 (my cells); WG flag := 1 ----
    { f16x2 z; z[0] = (_Float16)0.f; z[1] = (_Float16)0.f;
      st_ic_u32((unsigned int*)(hbuf + b * 512 + col),
                __builtin_bit_cast(unsigned int, z)); }
    __syncthreads();                      // drains vmcnt of all waves
    unsigned int* myflag = flags + (size_t)wg * 64;   // 256B spacing
    if (tid == 0) st_ic_u32(myflag, 1u);

    // wave wv consumes h-cols [128wv,128wv+128) of batch group BG,
    // produced by WGs (BG, 4wv+0..3): poll those 4 flags (lane&3).
    const unsigned int* pollp =
        flags + (size_t)(BG * 16 + wv * 4 + (lane & 3)) * 64;

    // ---- B fragments: wave wv's 8 n-tiles x 4 K-frags (128 VGPRs) ----
    f16x8 bfr[8][4];
    #pragma unroll
    for (int n = 0; n < 8; ++n) {
        const int rr = n * 16 + m16;
        const int gr = (rr >> 5) * 512 + CG * 32 + (rr & 31);
        const float* wrow = Whh + (size_t)gr * 512 + wv * 128 + q * 8;
        #pragma unroll
        for (int ks = 0; ks < 4; ++ks) {
            const f32x4 w0 = *(const f32x4*)(wrow + ks * 32);
            const f32x4 w1 = *(const f32x4*)(wrow + ks * 32 + 4);
            f16x8 bv;
            #pragma unroll
            for (int e = 0; e < 4; ++e) {
                bv[e]     = (_Float16)w0[e];
                bv[4 + e] = (_Float16)w1[e];
            }
            bfr[n][ks] = bv;
        }
    }

    // ---- P-row pipeline: ppv = row for step t; refilled post-release ----
    int tok1;
    f32x2 ppv[4];
    {
        const int tok0 = toks[0];
        const float* pp = P + (size_t)tok0 * 2048 + col;
        #pragma unroll
        for (int g = 0; g < 4; ++g) ppv[g] = *(const f32x2*)(pp + g * 512);
        tok1 = toks[1];
    }

    float c0 = 0.f, c1 = 0.f;

    for (int t = 0; t < 512; ++t) {
        const unsigned int tgt = (unsigned int)(t + 1);

        // ---- staggered 2-slot poll: samples every ~RT/2 instead of RT.
        //      slot B issued ~512cy (s_sleep 8) after A; loop alternates
        //      s_waitcnt vmcnt(1) on the older slot. Exit may leave one
        //      load in flight (drained by the A-load block's vmcnt(0);
        //      f0/f1 stay live as dummy inputs there). ----
        unsigned int f0, f1;
        asm volatile(
            "global_load_dword %0, %2, off sc1\n\t"
            "s_sleep 8\n\t"
            "global_load_dword %1, %2, off sc1\n\t"
            "Lpoll%=:\n\t"
            "s_waitcnt vmcnt(1)\n\t"
            "v_cmp_lt_u32 vcc, %0, %3\n\t"
            "s_cbranch_vccz Ldone%=\n\t"
            "global_load_dword %0, %2, off sc1\n\t"
            "s_waitcnt vmcnt(1)\n\t"
            "v_cmp_lt_u32 vcc, %1, %3\n\t"
            "s_cbranch_vccz Ldone%=\n\t"
            "global_load_dword %1, %2, off sc1\n\t"
            "s_branch Lpoll%=\n\t"
            "Ldone%=:\n\t"
            : "=&v"(f0), "=&v"(f1)
            : "v"(pollp), "v"(tgt)
            : "memory", "vcc");

        const _Float16* hsrc = hbuf + (size_t)(t & 1) * (64 * 512);
        _Float16*       hdst = hbuf + (size_t)((t + 1) & 1) * (64 * 512);

        // ---- A fragments: 4 x dwordx4 sc1 (4KB/wave from IC); vmcnt(0)
        //      also drains the P prefetch and the leftover poll slot ----
        u32x4 a0, a1, a2, a3;
        {
            const _Float16* ap =
                hsrc + (BG * 16 + m16) * 512 + wv * 128 + q * 8;
            asm volatile(
                "global_load_dwordx4 %0, %4, off sc1\n\t"
                "global_load_dwordx4 %1, %4, off offset:64 sc1\n\t"
                "global_load_dwordx4 %2, %4, off offset:128 sc1\n\t"
                "global_load_dwordx4 %3, %4, off offset:192 sc1\n\t"
                "s_waitcnt vmcnt(0)"
                : "=&v"(a0), "=&v"(a1), "=&v"(a2), "=&v"(a3)
                : "v"(ap), "v"(f0), "v"(f1)
                : "memory");
        }
        f16x8 af[4] = {
            __builtin_bit_cast(f16x8, a0), __builtin_bit_cast(f16x8, a1),
            __builtin_bit_cast(f16x8, a2), __builtin_bit_cast(f16x8, a3)
        };

        // ---- 32 MFMA: 8 n-tiles x 4 K-steps (my K-chunk partial) ----
        f32x4 acc[8] = {};
        #pragma unroll
        for (int ks = 0; ks < 4; ++ks)
            #pragma unroll
            for (int n = 0; n < 8; ++n)
                acc[n] = __builtin_amdgcn_mfma_f32_16x16x32_f16(
                    af[ks], bfr[n][ks], acc[n], 0, 0, 0);

        // ---- write partial S to LDS, batch granule rotated by (row>>3)&3:
        //      write slot p = (gq + row>>3)&3 — b128-preserving, 2-way ----
        {
            const int cl = lane & 15, gq = lane >> 4;
            #pragma unroll
            for (int n = 0; n < 8; ++n) {
                const int row = wv * 128 + n * 16 + cl;
                *(f32x4*)&Spart[row * 20 + ((gq + (row >> 3)) & 3) * 4] = acc[n];
            }
        }
        __syncthreads();                  // split-K reduction barrier

        // ---- gate inputs: sum 4 wave-partials per gate value (2-way) ----
        f32x2 sv[4];
        #pragma unroll
        for (int g = 0; g < 4; ++g) {
            f32x2 s = {0.f, 0.f};
            #pragma unroll
            for (int w = 0; w < 4; ++w) {
                const int r0 = w * 128 + g * 32 + cq;
                const int base =
                    r0 * 20 + (((bl >> 2) + (r0 >> 3)) & 3) * 4 + (bl & 3);
                s[0] += Spart[base];
                s[1] += Spart[base + 20]; // col cq+1: same rotation (cq even)
            }
            sv[g] = s;
        }

        // ---- gates (2 adjacent cols of one batch per thread) ----
        float hv[2];
        #pragma unroll
        for (int p = 0; p < 2; ++p) {
            const float iv = sigm_(sv[0][p] + gxv[0][p] + ppv[0][p]);
            const float fv = sigm_(sv[1][p] + gxv[1][p] + ppv[1][p]);
            const float gv = tanh_(sv[2][p] + gxv[2][p] + ppv[2][p]);
            const float ov = sigm_(sv[3][p] + gxv[3][p] + ppv[3][p]);
            float& c = p ? c1 : c0;
            c = fv * c + iv * gv;
            hv[p] = ov * tanh_(c);
        }

        f16x2 hh; hh[0] = (_Float16)hv[0]; hh[1] = (_Float16)hv[1];
        st_ic_u32((unsigned int*)(hdst + b * 512 + col),
                  __builtin_bit_cast(unsigned int, hh));
        if (t == last) {
            f32x2 o; o[0] = hv[0]; o[1] = hv[1];
            st_ic_u64((unsigned long long*)(hn + (size_t)b * 512 + col),
                      __builtin_bit_cast(unsigned long long, o));
        }

        // ---- release: barrier drains h/hn stores, then tid0 flag ----
        __syncthreads();
        if (tid == 0) st_ic_u32(myflag, (unsigned int)(t + 2));

        // ---- NEXT step's P row prefetch issued POST-release; its
        //      (possibly HBM-miss) latency sits in the poll window ----
        {
            const float* pn = P + (size_t)tok1 * 2048 + col;
            #pragma unroll
            for (int g = 0; g < 4; ++g)
                ppv[g] = *(const f32x2*)(pn + g * 512);
            tok1 = toks[t < 510 ? t + 2 : 511];
        }
    }

    // ======== fused epilogue: out = hn @ W_act^T + b_act ========
    // Wait for the whole clique (16 WGs of my BG) to finish (flag >= 513);
    // the per-step release order (bar2 drain -> flag) covers the hn stores.
    {
        const unsigned int* ep = flags + (size_t)(BG * 16 + (lane & 15)) * 64;
        while (true) {
            const unsigned int v = ld_ic_u32(ep);
            if (__all((int)(v >= 513u))) break;
        }
        asm volatile("" ::: "memory");

        // stage hn[16 batches][512] into LDS, pitch 516 (bank-safe)
        float* hnL = Spart;               // 16*516 f32 = 33024 B
        {
            const int r  = tid >> 4;
            const int c0 = (tid & 15) * 4;
            const float* src = hn + (size_t)(BG * 16 + r) * 512 + c0;
            float* dst = hnL + r * 516 + c0;
            u32x4 d0, d1, d2, d3, d4, d5, d6, d7;
            asm volatile(
                "global_load_dwordx4 %0, %8, off sc1\n\t"
                "global_load_dwordx4 %1, %8, off offset:256 sc1\n\t"
                "global_load_dwordx4 %2, %8, off offset:512 sc1\n\t"
                "global_load_dwordx4 %3, %8, off offset:768 sc1\n\t"
                "global_load_dwordx4 %4, %8, off offset:1024 sc1\n\t"
                "global_load_dwordx4 %5, %8, off offset:1280 sc1\n\t"
                "global_load_dwordx4 %6, %8, off offset:1536 sc1\n\t"
                "global_load_dwordx4 %7, %8, off offset:1792 sc1\n\t"
                "s_waitcnt vmcnt(0)"
                : "=&v"(d0), "=&v"(d1), "=&v"(d2), "=&v"(d3),
                  "=&v"(d4), "=&v"(d5), "=&v"(d6), "=&v"(d7)
                : "v"(src)
                : "memory");
            *(u32x4*)(dst)       = d0; *(u32x4*)(dst + 64)  = d1;
            *(u32x4*)(dst + 128) = d2; *(u32x4*)(dst + 192) = d3;
            *(u32x4*)(dst + 256) = d4; *(u32x4*)(dst + 320) = d5;
            *(u32x4*)(dst + 384) = d6; *(u32x4*)(dst + 448) = d7;
        }
        __syncthreads();

        // each thread: 2 out cols (col, col+1) for batch b
        const float* w0 = W_act + (size_t)col * 512;
        const float* w1 = w0 + 512;
        float s0 = b_act[col], s1 = b_act[col + 1];
        const float* h = hnL + bl * 516;
        #pragma unroll 4
        for (int k = 0; k < 512; k += 4) {
            const f32x4 hv4 = *(const f32x4*)(h + k);
            const f32x4 wa  = *(const f32x4*)(w0 + k);
            const f32x4 wb  = *(const f32x4*)(w1 + k);
            #pragma unroll
            for (int e = 0; e < 4; ++e) {
                s0 = fmaf(hv4[e], wa[e], s0);
                s1 = fmaf(hv4[e], wb[e], s1);
            }
        }
        f32x2 o; o[0] = s0; o[1] = s1;
        *(f32x2*)(out + (size_t)b * 512 + col) = o;
    }
}

// ---------------------------------------------------------------------------
extern "C" void kernel_launch(void* const* d_in, const int* in_sizes, int n_in,
                              void* d_out, int out_size, void* d_ws, size_t ws_size,
                              hipStream_t stream)
{
    const float* x1    = (const float*)d_in[0];   // [64,1024]
    const int*   x2    = (const int*)  d_in[1];   // [64,512]
    const int*   lens  = (const int*)  d_in[2];   // [64]
    const float* emb   = (const float*)d_in[3];   // [512,128]
    const float* W_ih  = (const float*)d_in[4];   // [2048,1152]
    const float* W_hh  = (const float*)d_in[5];   // [2048,512]
    const float* b_ih  = (const float*)d_in[6];   // [2048]
    const float* b_hh  = (const float*)d_in[7];   // [2048]
    const float* W_act = (const float*)d_in[8];   // [512,512]
    const float* b_act = (const float*)d_in[9];   // [512]
    float* out = (float*)d_out;                   // [64,512]

    char* ws = (char*)d_ws;
    float*        GX0   = (float*)(ws + WS_GX0);
    float*        P     = (float*)(ws + WS_P);
    float*        hn    = (float*)(ws + WS_HN);
    _Float16*     hbuf  = (_Float16*)(ws + WS_HBUF);
    unsigned int* flags = (unsigned int*)(ws + WS_FLAGS);

    // zero flags + GX0 (split-K accumulator); out is fully written in-kernel
    hipMemsetAsync(flags, 0, 16384, stream);
    hipMemsetAsync(GX0, 0, 64 * 2048 * sizeof(float), stream);

    // merged prologue: GX0 (blocks 0..127) + P (blocks 128..383)
    gemm_prologue<<<dim3(384), TPB, 0, stream>>>(
        x1, emb, W_ih, b_ih, b_hh, GX0, P);

    // recurrence + fused action head
    lstm_seq<<<NWG, TPB, 0, stream>>>(W_hh, GX0, P, x2, lens, hbuf, hn, flags,
                                      W_act, b_act, out);
}